// Round 9
// baseline (860.041 us; speedup 1.0000x reference)
//
#include <hip/hip_runtime.h>

#define NN 10000
#define EE 80000
#define DD 128
#define SLOTS 64
#define GRID 256
#define NTILE 625    // EE/128
#define NVB 2500     // NN/4
#define NPRE 5441    // 5000 init + 128 wt + 313 fill

typedef short bf16x8 __attribute__((ext_vector_type(8)));
typedef float f32x4 __attribute__((ext_vector_type(4)));

__device__ __forceinline__ float b2f(uint u){ u <<= 16; return __builtin_bit_cast(float, u); }
__device__ __forceinline__ ushort f2b(float f){
  uint u = __builtin_bit_cast(uint, f);
  u += 0x7fffu + ((u >> 16) & 1u);           // RNE
  return (ushort)(u >> 16);
}
__device__ __forceinline__ uint pack2(float a, float b){
  return (uint)f2b(a) | ((uint)f2b(b) << 16);
}

// Manual grid barrier: monotonic counter, device-scope atomics.
// All GRID blocks are resident (256 blocks, 64KB LDS -> 512 residency slots),
// so the spin cannot deadlock. __threadfence (agent scope) gives the L2
// writeback/invalidate needed for cross-XCD visibility of plain stores.
__device__ __forceinline__ void gbar(int* bar, int expect){
  __syncthreads();
  __threadfence();
  if (threadIdx.x == 0){
    atomicAdd(bar, 1);
    while (atomicAdd(bar, 0) < expect){ __builtin_amdgcn_s_sleep(8); }
  }
  __syncthreads();
  __threadfence();
}

// One dispatch; phases separated by gbar(). 256 blocks x 256 thr; LDS 64KB.
__global__ __launch_bounds__(256, 2) void k_all(
    const float* __restrict__ x, const int* __restrict__ dst,
    const float* __restrict__ W1, const float* __restrict__ b1,
    const float* __restrict__ W2, const float* __restrict__ b2,
    ushort* __restrict__ lgX, float* __restrict__ A, ushort* __restrict__ Wt,
    int* bar, int* __restrict__ cnt, int* __restrict__ inl, float* __restrict__ out)
{
  __shared__ uint4 smW[2048];   // W1 bf16 [n][k], 16B-granule XOR swizzle g^(n&7)
  __shared__ uint4 smT[2048];   // t tile 128x128 bf16, same swizzle (own-wave rows only)
  const int tid = threadIdx.x;
  const int bid = blockIdx.x;
  const int lane = tid & 63;
  const int w = tid >> 6;
  const int rlo = lane & 15;
  const int khi = lane >> 4;
  const bf16x8* smWb = (const bf16x8*)smW;
  const bf16x8* smTb = (const bf16x8*)smT;
  uint* smTu = (uint*)smT;
  int bexp = 0;

  // ---- P1: init lgX | transpose W -> bf16 | CSR fill (verified k_pre bodies) ----
  for (int u = bid; u < NPRE; u += GRID){
    if (u < 5000){
      int i = u * 16 + (tid >> 4);
      int g = tid & 15;
      int s = i >> 3, d = dst[i];
      const float4* xs = (const float4*)(x + s * DD + g * 8);
      const float4* xd = (const float4*)(x + d * DD + g * 8);
      float4 s0 = xs[0], s1 = xs[1], d0 = xd[0], d1 = xd[1];
      uint4 o;
      o.x = pack2(0.5f * (s0.x + d0.x), 0.5f * (s0.y + d0.y));
      o.y = pack2(0.5f * (s0.z + d0.z), 0.5f * (s0.w + d0.w));
      o.z = pack2(0.5f * (s1.x + d1.x), 0.5f * (s1.y + d1.y));
      o.w = pack2(0.5f * (s1.z + d1.z), 0.5f * (s1.w + d1.w));
      *(uint4*)(lgX + i * DD + g * 8) = o;
    } else if (u < 5128){
      int idx = (u - 5000) * 256 + tid;        // 0..32767
      int which = idx >> 14;
      int r = idx & 16383;
      int k = r >> 7, n = r & 127;
      const float* W = which ? W2 : W1;
      Wt[which * 16384 + n * DD + k] = f2b(W[r]);
    } else {
      int i = (u - 5128) * 256 + tid;
      if (i < EE){
        int d = dst[i];
        int pos = atomicAdd(&cnt[d], 1);
        if (pos < SLOTS) inl[d * SLOTS + pos] = i;
      }
    }
  }
  bexp += GRID; gbar(bar, bexp);

  // ---- stage W1 into smW once (persists; next gbar's syncthreads orders use) ----
  #pragma unroll
  for (int it = 0; it < 8; ++it){
    int gi = it * 256 + tid;                   // uint4 index 0..2047
    int r = gi >> 4, g = gi & 15;
    smW[r * 16 + (g ^ (r & 7))] = *(const uint4*)(Wt + gi * 8);
  }

  for (int iter = 0; iter < 3; ++iter){
    // ---- P2: A[v] = sum over in-edges e of relu(lgX[e] + x[v])  (verified k_aggr) ----
    for (int vb = bid; vb < NVB; vb += GRID){
      int v = vb * 4 + (tid >> 6);
      float2 xv = *(const float2*)(x + v * DD + lane * 2);
      int n = cnt[v]; if (n > SLOTS) n = SLOTS;
      float ax = 0.f, ay = 0.f;
      const int* ip = inl + v * SLOTS;
      for (int t = 0; t < n; ++t){
        int e = ip[t];
        uint u = *(const uint*)(lgX + e * DD + lane * 2);
        ax += fmaxf(b2f(u & 0xffffu) + xv.x, 0.f);
        ay += fmaxf(b2f(u >> 16)     + xv.y, 0.f);
      }
      float2 r; r.x = ax; r.y = ay;
      *(float2*)(A + v * DD + lane * 2) = r;
    }
    bexp += GRID; gbar(bar, bexp);

    // ---- P3: lgX = relu((lgX + A[src]) @ W1 + b1) @ W2 + b2  (verified k_gemm, in-place) ----
    for (int tb = bid; tb < NTILE; tb += GRID){
      const int row0 = tb * 128;

      // h fragments from global (own rows only; reads complete into regs before stores)
      bf16x8 hfrag[2][4];
      #pragma unroll
      for (int mb = 0; mb < 2; ++mb){
        int row = row0 + (2 * w + mb) * 16 + rlo;
        const ushort* lp = lgX + row * DD;
        const float*  ap = A + (row >> 3) * DD;
        #pragma unroll
        for (int s = 0; s < 4; ++s){
          int k0 = s * 32 + khi * 8;
          uint4 lx = *(const uint4*)(lp + k0);
          float4 a0 = *(const float4*)(ap + k0);
          float4 a1 = *(const float4*)(ap + k0 + 4);
          uint uu[4] = {lx.x, lx.y, lx.z, lx.w};
          float av[8] = {a0.x, a0.y, a0.z, a0.w, a1.x, a1.y, a1.z, a1.w};
          uint4 o;
          o.x = pack2(b2f(uu[0] & 0xffffu) + av[0], b2f(uu[0] >> 16) + av[1]);
          o.y = pack2(b2f(uu[1] & 0xffffu) + av[2], b2f(uu[1] >> 16) + av[3]);
          o.z = pack2(b2f(uu[2] & 0xffffu) + av[4], b2f(uu[2] >> 16) + av[5]);
          o.w = pack2(b2f(uu[3] & 0xffffu) + av[6], b2f(uu[3] >> 16) + av[7]);
          hfrag[mb][s] = __builtin_bit_cast(bf16x8, o);
        }
      }

      // GEMM1 (swapped): acc1 = W1t x h^T
      f32x4 acc1[2][8];
      #pragma unroll
      for (int mb = 0; mb < 2; ++mb)
        #pragma unroll
        for (int nf = 0; nf < 8; ++nf) acc1[mb][nf] = (f32x4){0.f, 0.f, 0.f, 0.f};
      #pragma unroll
      for (int s = 0; s < 4; ++s){
        #pragma unroll
        for (int nf = 0; nf < 8; ++nf){
          int r = nf * 16 + rlo;
          int g = s * 4 + khi;
          bf16x8 wf = smWb[r * 16 + (g ^ (r & 7))];
          acc1[0][nf] = __builtin_amdgcn_mfma_f32_16x16x32_bf16(wf, hfrag[0][s], acc1[0][nf], 0, 0, 0);
          acc1[1][nf] = __builtin_amdgcn_mfma_f32_16x16x32_bf16(wf, hfrag[1][s], acc1[1][nf], 0, 0, 0);
        }
      }

      // epilogue1: t = relu(acc1+b1) -> smT own rows (packed u32 pairs, wave-local)
      #pragma unroll
      for (int mb = 0; mb < 2; ++mb){
        int row = (2 * w + mb) * 16 + rlo;
        int rsw = row & 7;
        #pragma unroll
        for (int nf = 0; nf < 8; ++nf){
          float4 bb = *(const float4*)(b1 + nf * 16 + khi * 4);
          float t0 = fmaxf(acc1[mb][nf][0] + bb.x, 0.f);
          float t1 = fmaxf(acc1[mb][nf][1] + bb.y, 0.f);
          float t2 = fmaxf(acc1[mb][nf][2] + bb.z, 0.f);
          float t3 = fmaxf(acc1[mb][nf][3] + bb.w, 0.f);
          int u0 = nf * 8 + khi * 2;
          int g0 = u0 >> 2;
          int base = row * 64 + ((g0 ^ rsw) << 2) + (u0 & 3);
          smTu[base]     = pack2(t0, t1);
          smTu[base + 1] = pack2(t2, t3);
        }
      }

      // GEMM2 (swapped): W2t rows from global (L2-hot), t from own LDS rows
      f32x4 acc2[2][8];
      #pragma unroll
      for (int mb = 0; mb < 2; ++mb)
        #pragma unroll
        for (int nf = 0; nf < 8; ++nf) acc2[mb][nf] = (f32x4){0.f, 0.f, 0.f, 0.f};
      #pragma unroll
      for (int s = 0; s < 4; ++s){
        bf16x8 tf[2];
        #pragma unroll
        for (int mb = 0; mb < 2; ++mb){
          int row = (2 * w + mb) * 16 + rlo;
          int g = s * 4 + khi;
          tf[mb] = smTb[row * 16 + (g ^ (row & 7))];
        }
        #pragma unroll
        for (int nf = 0; nf < 8; ++nf){
          bf16x8 wf = *(const bf16x8*)(Wt + 16384 + (nf * 16 + rlo) * DD + s * 32 + khi * 8);
          acc2[0][nf] = __builtin_amdgcn_mfma_f32_16x16x32_bf16(wf, tf[0], acc2[0][nf], 0, 0, 0);
          acc2[1][nf] = __builtin_amdgcn_mfma_f32_16x16x32_bf16(wf, tf[1], acc2[1][nf], 0, 0, 0);
        }
      }

      // epilogue2: out = acc2 + b2 -> smT own rows (after own reads; per-wave in-order)
      #pragma unroll
      for (int mb = 0; mb < 2; ++mb){
        int row = (2 * w + mb) * 16 + rlo;
        int rsw = row & 7;
        #pragma unroll
        for (int nf = 0; nf < 8; ++nf){
          float4 bb = *(const float4*)(b2 + nf * 16 + khi * 4);
          float t0 = acc2[mb][nf][0] + bb.x;
          float t1 = acc2[mb][nf][1] + bb.y;
          float t2 = acc2[mb][nf][2] + bb.z;
          float t3 = acc2[mb][nf][3] + bb.w;
          int u0 = nf * 8 + khi * 2;
          int g0 = u0 >> 2;
          int base = row * 64 + ((g0 ^ rsw) << 2) + (u0 & 3);
          smTu[base]     = pack2(t0, t1);
          smTu[base + 1] = pack2(t2, t3);
        }
      }
      // read back own rows -> coalesced in-place store
      #pragma unroll
      for (int mb = 0; mb < 2; ++mb){
        int row = (2 * w + mb) * 16 + rlo;
        #pragma unroll
        for (int s = 0; s < 4; ++s){
          int g = s * 4 + khi;
          uint4 val = smT[row * 16 + (g ^ (row & 7))];
          *(uint4*)(lgX + (row0 + row) * DD + s * 32 + khi * 8) = val;
        }
      }
    }
    bexp += GRID; gbar(bar, bexp);
  }

  // ---- P4: out[v] = relu(mean over in-edges of lgX[e])  (verified k_final) ----
  for (int vb = bid; vb < NVB; vb += GRID){
    int v = vb * 4 + (tid >> 6);
    int n = cnt[v]; if (n > SLOTS) n = SLOTS;
    float ax = 0.f, ay = 0.f;
    const int* ip = inl + v * SLOTS;
    for (int t = 0; t < n; ++t){
      int e = ip[t];
      uint u = *(const uint*)(lgX + e * DD + lane * 2);
      ax += b2f(u & 0xffffu);
      ay += b2f(u >> 16);
    }
    float inv = 1.f / (float)(n > 0 ? n : 1);
    float2 r; r.x = fmaxf(ax * inv, 0.f); r.y = fmaxf(ay * inv, 0.f);
    *(float2*)(out + v * DD + lane * 2) = r;
  }
}

extern "C" void kernel_launch(void* const* d_in, const int* in_sizes, int n_in,
                              void* d_out, int out_size, void* d_ws, size_t ws_size,
                              hipStream_t stream){
  (void)in_sizes; (void)n_in; (void)out_size; (void)ws_size;
  const float* x  = (const float*)d_in[0];
  const int*   ei = (const int*)d_in[1];
  const int*   dst = ei + EE;
  const float* W1 = (const float*)d_in[4];
  const float* b1 = (const float*)d_in[5];
  const float* W2 = (const float*)d_in[6];
  const float* b2 = (const float*)d_in[7];
  float* out = (float*)d_out;

  char* ws = (char*)d_ws;
  ushort* lgX = (ushort*)ws;                      // E*128 bf16   = 20,480,000 B
  float*  A   = (float*)(ws + 20480000);          // N*128 f32    =  5,120,000 B
  ushort* Wt  = (ushort*)(ws + 25600000);         // 2*128*128 bf16 =   65,536 B
  int*    bar = (int*)(ws + 25665536);            // 8 ints (barrier counter)
  int*    cnt = (int*)(ws + 25665568);            // N int        =     40,000 B
  int*    inl = (int*)(ws + 25705568);            // N*64 int     =  2,560,000 B

  hipMemsetAsync(bar, 0, 32 + NN * sizeof(int), stream);   // zero bar + cnt
  k_all<<<GRID, 256, 0, stream>>>(x, dst, W1, b1, W2, b2, lgX, A, Wt, bar, cnt, inl, out);
}

// Round 10
// 255.892 us; speedup vs baseline: 3.3610x; 3.3610x over previous
//
#include <hip/hip_runtime.h>

#define NN 10000
#define EE 80000
#define DD 128

typedef short bf16x8 __attribute__((ext_vector_type(8)));
typedef float f32x4 __attribute__((ext_vector_type(4)));

__device__ __forceinline__ float b2f(uint u){ u <<= 16; return __builtin_bit_cast(float, u); }
__device__ __forceinline__ ushort f2b(float f){
  uint u = __builtin_bit_cast(uint, f);
  u += 0x7fffu + ((u >> 16) & 1u);           // RNE
  return (ushort)(u >> 16);
}
__device__ __forceinline__ uint pack2(float a, float b){
  return (uint)f2b(a) | ((uint)f2b(b) << 16);
}

// ---------- D2: Wt transpose (blocks 0..127) | per-dst count (blocks 128..440) ----------
__global__ __launch_bounds__(256) void k_prep(const float* __restrict__ W1, const float* __restrict__ W2,
                                              const int* __restrict__ dst,
                                              ushort* __restrict__ Wt, int* __restrict__ cnt){
  int b = blockIdx.x, tid = threadIdx.x;
  if (b < 128){
    int idx = b * 256 + tid;                  // 0..32767
    int which = idx >> 14;
    int r = idx & 16383;
    int k = r >> 7, n = r & 127;
    const float* W = which ? W2 : W1;
    Wt[which * 16384 + n * DD + k] = f2b(W[r]);
  } else {
    int i = (b - 128) * 256 + tid;
    if (i < EE) atomicAdd(&cnt[dst[i]], 1);
  }
}

// ---------- D3: exclusive scan -> start[0..NN], pos=start ----------
__global__ __launch_bounds__(256) void k_scan(const int* __restrict__ cnt,
                                              int* __restrict__ start, int* __restrict__ pos){
  __shared__ int part[256];
  int t = threadIdx.x;
  int c0 = t * 40, c1 = c0 + 40; if (c1 > NN) c1 = NN; if (c0 > NN) c0 = NN;
  int s = 0;
  for (int i = c0; i < c1; ++i) s += cnt[i];
  part[t] = s;
  __syncthreads();
  if (t == 0){
    int acc = 0;
    for (int i = 0; i < 256; ++i){ int v = part[i]; part[i] = acc; acc += v; }
  }
  __syncthreads();
  int acc = part[t];
  for (int i = c0; i < c1; ++i){ start[i] = acc; pos[i] = acc; acc += cnt[i]; }
  if (t == 255) start[NN] = EE;
}

// ---------- D4: build permutation: slot -> (src, dst) ----------
__global__ __launch_bounds__(256) void k_build(const int* __restrict__ dst, int* __restrict__ pos,
                                               int* __restrict__ srcOf, int* __restrict__ dstOf){
  int i = blockIdx.x * 256 + threadIdx.x;
  if (i < EE){
    int d = dst[i];
    int slot = atomicAdd(&pos[d], 1);
    srcOf[slot] = i >> 3;
    dstOf[slot] = d;
  }
}

// ---------- D5: init lgX (permuted rows): lgX[r] = bf16(0.5*(x[srcOf[r]] + x[dstOf[r]])) ----------
__global__ __launch_bounds__(256) void k_init(const float* __restrict__ x,
                                              const int* __restrict__ srcOf, const int* __restrict__ dstOf,
                                              ushort* __restrict__ lgX){
  int tid = threadIdx.x;
  int r = blockIdx.x * 16 + (tid >> 4);
  int g = tid & 15;
  int s = srcOf[r], d = dstOf[r];
  const float4* xs = (const float4*)(x + s * DD + g * 8);
  const float4* xd = (const float4*)(x + d * DD + g * 8);
  float4 s0 = xs[0], s1 = xs[1], d0 = xd[0], d1 = xd[1];
  uint4 o;
  o.x = pack2(0.5f * (s0.x + d0.x), 0.5f * (s0.y + d0.y));
  o.y = pack2(0.5f * (s0.z + d0.z), 0.5f * (s0.w + d0.w));
  o.z = pack2(0.5f * (s1.x + d1.x), 0.5f * (s1.y + d1.y));
  o.w = pack2(0.5f * (s1.z + d1.z), 0.5f * (s1.w + d1.w));
  *(uint4*)(lgX + r * DD + g * 8) = o;
}

// ---------- aggr: A[v] = sum over contiguous segment rows of relu(lgX[r] + x[v]) ----------
__global__ __launch_bounds__(256) void k_aggr(const ushort* __restrict__ lgX, const float* __restrict__ x,
                                              const int* __restrict__ start, float* __restrict__ A){
  int lane = threadIdx.x & 63;
  int v = blockIdx.x * 4 + (threadIdx.x >> 6);
  float2 xv = *(const float2*)(x + v * DD + lane * 2);
  int r0 = start[v], r1 = start[v + 1];
  float ax = 0.f, ay = 0.f;
  for (int r = r0; r < r1; ++r){
    uint u = *(const uint*)(lgX + r * DD + lane * 2);
    ax += fmaxf(b2f(u & 0xffffu) + xv.x, 0.f);
    ay += fmaxf(b2f(u >> 16)     + xv.y, 0.f);
  }
  float2 rr; rr.x = ax; rr.y = ay;
  *(float2*)(A + v * DD + lane * 2) = rr;
}

// ---------- final: out[v] = relu(mean over segment rows of lgX[r]) ----------
__global__ __launch_bounds__(256) void k_final(const ushort* __restrict__ lgX,
                                               const int* __restrict__ start, float* __restrict__ out){
  int lane = threadIdx.x & 63;
  int v = blockIdx.x * 4 + (threadIdx.x >> 6);
  int r0 = start[v], r1 = start[v + 1];
  int n = r1 - r0;
  float ax = 0.f, ay = 0.f;
  for (int r = r0; r < r1; ++r){
    uint u = *(const uint*)(lgX + r * DD + lane * 2);
    ax += b2f(u & 0xffffu);
    ay += b2f(u >> 16);
  }
  float inv = 1.f / (float)(n > 0 ? n : 1);
  float2 rr; rr.x = fmaxf(ax * inv, 0.f); rr.y = fmaxf(ay * inv, 0.f);
  *(float2*)(out + v * DD + lane * 2) = rr;
}

// ---------- fused double-swapped GEMM (verified R2/R5 body; A gathered via srcOf) ----------
// lgX = relu((lgX + A[srcOf[row]]) @ W1 + b1) @ W2 + b2, in-place, 128 rows/block.
// LDS 64KB = W1(32K,swz) + t-tile(32K,swz). One __syncthreads total.
__global__ __launch_bounds__(256) void k_gemm(ushort* __restrict__ lgX, const float* __restrict__ A,
                                              const int* __restrict__ srcOf,
                                              const ushort* __restrict__ Wt,
                                              const float* __restrict__ b1, const float* __restrict__ b2){
  __shared__ uint4 smW[2048];   // W1 bf16 [n][k], 16B-granule XOR swizzle g^(n&7)
  __shared__ uint4 smT[2048];   // t tile 128x128 bf16, same swizzle (own-wave rows only)
  const int tid = threadIdx.x;
  const int lane = tid & 63;
  const int w = tid >> 6;
  const int rlo = lane & 15;
  const int khi = lane >> 4;
  const int row0 = blockIdx.x * 128;
  const bf16x8* smWb = (const bf16x8*)smW;
  const bf16x8* smTb = (const bf16x8*)smT;
  uint* smTu = (uint*)smT;

  // stage W1 into LDS (swizzled)
  #pragma unroll
  for (int it = 0; it < 8; ++it){
    int gi = it * 256 + tid;                 // uint4 index 0..2047
    int r = gi >> 4, g = gi & 15;
    smW[r * 16 + (g ^ (r & 7))] = *(const uint4*)(Wt + gi * 8);
  }

  // h fragments from global: h[row][k] = lgX[row][k] + A[srcOf[row]][k]
  bf16x8 hfrag[2][4];
  #pragma unroll
  for (int mb = 0; mb < 2; ++mb){
    int row = row0 + (2 * w + mb) * 16 + rlo;
    const ushort* lp = lgX + row * DD;
    const float*  ap = A + srcOf[row] * DD;
    #pragma unroll
    for (int s = 0; s < 4; ++s){
      int k0 = s * 32 + khi * 8;
      uint4 lx = *(const uint4*)(lp + k0);
      float4 a0 = *(const float4*)(ap + k0);
      float4 a1 = *(const float4*)(ap + k0 + 4);
      uint uu[4] = {lx.x, lx.y, lx.z, lx.w};
      float av[8] = {a0.x, a0.y, a0.z, a0.w, a1.x, a1.y, a1.z, a1.w};
      uint4 o;
      o.x = pack2(b2f(uu[0] & 0xffffu) + av[0], b2f(uu[0] >> 16) + av[1]);
      o.y = pack2(b2f(uu[1] & 0xffffu) + av[2], b2f(uu[1] >> 16) + av[3]);
      o.z = pack2(b2f(uu[2] & 0xffffu) + av[4], b2f(uu[2] >> 16) + av[5]);
      o.w = pack2(b2f(uu[3] & 0xffffu) + av[6], b2f(uu[3] >> 16) + av[7]);
      hfrag[mb][s] = __builtin_bit_cast(bf16x8, o);
    }
  }
  __syncthreads();   // W1 staged

  // GEMM1 (swapped): acc1 = W1t x h^T
  f32x4 acc1[2][8];
  #pragma unroll
  for (int mb = 0; mb < 2; ++mb)
    #pragma unroll
    for (int nf = 0; nf < 8; ++nf) acc1[mb][nf] = (f32x4){0.f, 0.f, 0.f, 0.f};
  #pragma unroll
  for (int s = 0; s < 4; ++s){
    #pragma unroll
    for (int nf = 0; nf < 8; ++nf){
      int r = nf * 16 + rlo;
      int g = s * 4 + khi;
      bf16x8 wf = smWb[r * 16 + (g ^ (r & 7))];
      acc1[0][nf] = __builtin_amdgcn_mfma_f32_16x16x32_bf16(wf, hfrag[0][s], acc1[0][nf], 0, 0, 0);
      acc1[1][nf] = __builtin_amdgcn_mfma_f32_16x16x32_bf16(wf, hfrag[1][s], acc1[1][nf], 0, 0, 0);
    }
  }

  // epilogue1: t = relu(acc1+b1) -> smT own rows (packed u32 pairs, wave-local)
  #pragma unroll
  for (int mb = 0; mb < 2; ++mb){
    int row = (2 * w + mb) * 16 + rlo;
    int rsw = row & 7;
    #pragma unroll
    for (int nf = 0; nf < 8; ++nf){
      float4 bb = *(const float4*)(b1 + nf * 16 + khi * 4);
      float t0 = fmaxf(acc1[mb][nf][0] + bb.x, 0.f);
      float t1 = fmaxf(acc1[mb][nf][1] + bb.y, 0.f);
      float t2 = fmaxf(acc1[mb][nf][2] + bb.z, 0.f);
      float t3 = fmaxf(acc1[mb][nf][3] + bb.w, 0.f);
      int u0 = nf * 8 + khi * 2;
      int g0 = u0 >> 2;
      int base = row * 64 + ((g0 ^ rsw) << 2) + (u0 & 3);
      smTu[base]     = pack2(t0, t1);
      smTu[base + 1] = pack2(t2, t3);
    }
  }

  // GEMM2 (swapped): W2t rows from global (L2-hot), t from own LDS rows
  f32x4 acc2[2][8];
  #pragma unroll
  for (int mb = 0; mb < 2; ++mb)
    #pragma unroll
    for (int nf = 0; nf < 8; ++nf) acc2[mb][nf] = (f32x4){0.f, 0.f, 0.f, 0.f};
  #pragma unroll
  for (int s = 0; s < 4; ++s){
    bf16x8 tf[2];
    #pragma unroll
    for (int mb = 0; mb < 2; ++mb){
      int row = (2 * w + mb) * 16 + rlo;
      int g = s * 4 + khi;
      tf[mb] = smTb[row * 16 + (g ^ (row & 7))];
    }
    #pragma unroll
    for (int nf = 0; nf < 8; ++nf){
      bf16x8 wf = *(const bf16x8*)(Wt + 16384 + (nf * 16 + rlo) * DD + s * 32 + khi * 8);
      acc2[0][nf] = __builtin_amdgcn_mfma_f32_16x16x32_bf16(wf, tf[0], acc2[0][nf], 0, 0, 0);
      acc2[1][nf] = __builtin_amdgcn_mfma_f32_16x16x32_bf16(wf, tf[1], acc2[1][nf], 0, 0, 0);
    }
  }

  // epilogue2: out = acc2 + b2 -> smT own rows (after own reads; per-wave in-order)
  #pragma unroll
  for (int mb = 0; mb < 2; ++mb){
    int row = (2 * w + mb) * 16 + rlo;
    int rsw = row & 7;
    #pragma unroll
    for (int nf = 0; nf < 8; ++nf){
      float4 bb = *(const float4*)(b2 + nf * 16 + khi * 4);
      float t0 = acc2[mb][nf][0] + bb.x;
      float t1 = acc2[mb][nf][1] + bb.y;
      float t2 = acc2[mb][nf][2] + bb.z;
      float t3 = acc2[mb][nf][3] + bb.w;
      int u0 = nf * 8 + khi * 2;
      int g0 = u0 >> 2;
      int base = row * 64 + ((g0 ^ rsw) << 2) + (u0 & 3);
      smTu[base]     = pack2(t0, t1);
      smTu[base + 1] = pack2(t2, t3);
    }
  }
  // read back own rows -> coalesced in-place store
  #pragma unroll
  for (int mb = 0; mb < 2; ++mb){
    int row = (2 * w + mb) * 16 + rlo;
    #pragma unroll
    for (int s = 0; s < 4; ++s){
      int g = s * 4 + khi;
      uint4 val = smT[row * 16 + (g ^ (row & 7))];
      *(uint4*)(lgX + (row0 + row) * DD + s * 32 + khi * 8) = val;
    }
  }
}

extern "C" void kernel_launch(void* const* d_in, const int* in_sizes, int n_in,
                              void* d_out, int out_size, void* d_ws, size_t ws_size,
                              hipStream_t stream){
  (void)in_sizes; (void)n_in; (void)out_size; (void)ws_size;
  const float* x  = (const float*)d_in[0];
  const int*   ei = (const int*)d_in[1];
  const int*   dst = ei + EE;
  const float* W1 = (const float*)d_in[4];
  const float* b1 = (const float*)d_in[5];
  const float* W2 = (const float*)d_in[6];
  const float* b2 = (const float*)d_in[7];
  float* out = (float*)d_out;

  char* ws = (char*)d_ws;
  ushort* lgX   = (ushort*)ws;                    // E*128 bf16   = 20,480,000 B
  float*  A     = (float*)(ws + 20480000);        // N*128 f32    =  5,120,000 B
  ushort* Wt    = (ushort*)(ws + 25600000);       // 2*128*128 bf16 =   65,536 B
  int*    start = (int*)(ws + 25665536);          // (N+1) int    ->    40,960 B
  int*    pos   = (int*)(ws + 25706496);          // N int        =     40,000 B
  int*    cnt   = (int*)(ws + 25746496);          // N int        =     40,000 B
  int*    srcOf = (int*)(ws + 25786496);          // E int        =    320,000 B
  int*    dstOf = (int*)(ws + 26106496);          // E int        =    320,000 B

  hipMemsetAsync(cnt, 0, NN * sizeof(int), stream);
  k_prep<<<441, 256, 0, stream>>>(W1, W2, dst, Wt, cnt);
  k_scan<<<1, 256, 0, stream>>>(cnt, start, pos);
  k_build<<<313, 256, 0, stream>>>(dst, pos, srcOf, dstOf);
  k_init<<<EE / 16, 256, 0, stream>>>(x, srcOf, dstOf, lgX);
  for (int it = 0; it < 3; ++it){
    k_aggr<<<NN / 4, 256, 0, stream>>>(lgX, x, start, A);
    k_gemm<<<EE / 128, 256, 0, stream>>>(lgX, A, srcOf, Wt, b1, b2);
  }
  k_final<<<NN / 4, 256, 0, stream>>>(lgX, start, out);
}